// Round 12
// baseline (299.403 us; speedup 1.0000x reference)
//
#include <hip/hip_runtime.h>
#include <math.h>

#define CH 512
#define P 8
#define PLANE 4096   // 64*64
#define EPS 1e-5f

typedef float f4 __attribute__((ext_vector_type(4)));

__device__ __forceinline__ float leaky(float x) { return x >= 0.f ? x : 0.01f * x; }

__device__ __forceinline__ float wave_sum(float v) {
    #pragma unroll
    for (int off = 32; off; off >>= 1) v += __shfl_xor(v, off, 64);
    return v;
}

// ---------------- Kernel 1a: s_d means + pk dot + S ----------------
// grid = N, block = 64
__global__ __launch_bounds__(64) void sd_pk_kernel(
    const float* __restrict__ style,   // [N,512,4,4]
    const float* __restrict__ pk_w,    // [8,512]
    const float* __restrict__ pk_b,    // [8]
    float* __restrict__ sd_out,        // [N,512]
    float* __restrict__ S_out)         // [N]
{
    const int n = blockIdx.x;
    const int lane = threadIdx.x;
    const float4* sp = (const float4*)(style + (size_t)n * 8192);
    float sd[8];
    #pragma unroll
    for (int i = 0; i < 8; ++i) {
        int c = lane + 64 * i;
        float4 a = sp[c * 4 + 0], b = sp[c * 4 + 1];
        float4 d = sp[c * 4 + 2], e = sp[c * 4 + 3];
        float s = a.x + a.y + a.z + a.w + b.x + b.y + b.z + b.w
                + d.x + d.y + d.z + d.w + e.x + e.y + e.z + e.w;
        sd[i] = s * (1.f / 16.f);
        sd_out[n * 512 + c] = sd[i];
    }
    float Ssum = 0.f;
    #pragma unroll
    for (int o = 0; o < 8; ++o) {
        float acc = 0.f;
        #pragma unroll
        for (int i = 0; i < 8; ++i)
            acc += pk_w[o * 512 + lane + 64 * i] * sd[i];
        Ssum += wave_sum(acc) + pk_b[o];
    }
    if (lane == 0) S_out[n] = Ssum;
}

// ---------------- Kernel 1b: depthwise-kernel predictor conv ----------------
// one wave per (n, j, tap); grid = 16*72/4 = 288, block = 256
__global__ __launch_bounds__(256) void dconv_kernel(
    const float* __restrict__ style,   // [N,512,4,4]
    const float* __restrict__ dw_w,    // [8,512,2,2]
    const float* __restrict__ dw_b,    // [8]
    float* __restrict__ d_pred)        // [N,72]
{
    const int W = blockIdx.x * 4 + (threadIdx.x >> 6);
    const int lane = threadIdx.x & 63;
    const int n = W / 72, r = W % 72;
    const int j = r / 9, pos = r % 9, y = pos / 3, x = pos % 3;
    const float* sb = style + (size_t)n * 8192;
    const float4* wp = (const float4*)dw_w;
    float acc = 0.f;
    #pragma unroll
    for (int i = 0; i < 8; ++i) {
        int c = lane + 64 * i;
        float4 w = wp[j * 512 + c];
        const float* s = sb + c * 16 + y * 4 + x;
        acc += s[0] * w.x + s[1] * w.y + s[4] * w.z + s[5] * w.w;
    }
    acc = wave_sum(acc);
    if (lane == 0) d_pred[n * 72 + r] = leaky(acc + dw_b[j]);
}

// ---------------- Kernel 1c: bias GEMV ----------------
// one wave per output channel c, all 16 n; grid = 512/4 = 128, block = 256
__global__ __launch_bounds__(256) void bias_kernel(
    const float* __restrict__ sd,      // [N,512]
    const float* __restrict__ pb_w,    // [512,512]
    const float* __restrict__ pb_b,    // [512]
    float* __restrict__ bias_out)      // [N,512]
{
    const int c = blockIdx.x * 4 + (threadIdx.x >> 6);
    const int lane = threadIdx.x & 63;
    float w[8];
    #pragma unroll
    for (int i = 0; i < 8; ++i) w[i] = pb_w[(size_t)c * 512 + lane + 64 * i];
    float acc[16];
    #pragma unroll
    for (int nn = 0; nn < 16; ++nn) acc[nn] = 0.f;
    #pragma unroll
    for (int i = 0; i < 8; ++i) {
        #pragma unroll
        for (int nn = 0; nn < 16; ++nn)
            acc[nn] += w[i] * sd[nn * 512 + lane + 64 * i];
    }
    #pragma unroll
    for (int nn = 0; nn < 16; ++nn) acc[nn] = wave_sum(acc[nn]);
    if (lane == 0) {
        float bb = pb_b[c];
        #pragma unroll
        for (int nn = 0; nn < 16; ++nn) bias_out[nn * 512 + c] = acc[nn] + bb;
    }
}

// ---------------- Kernel 2: fused stats + conv + pointwise-collapse + IN ----
// One persistent block per (n, group): grid = 16*64 = 1024, block = 256.
// Phase 1: in-block IN stats (single HBM pass over the block's 8 planes).
// Phase 2: direct-load shfl-halo conv; re-reads L3-served (R11: FETCH 92 MB).
// VGPR control: unroll-2 channel loop (small prefetch window), hoisted row
// offsets, soft cap (256,4). R11's 228-VGPR/2-wave occupancy was the cost.
__global__ __launch_bounds__(256, 4) void main_kernel(
    const float* __restrict__ content,   // [N,512,64,64]
    const float* __restrict__ d_pred,    // [N,72]
    const float* __restrict__ S_in,      // [N]
    const float* __restrict__ bias_in,   // [N,512]
    float* __restrict__ out)             // [N,512,64,64]
{
    const int b = blockIdx.x;
    const int g = b & 63, n = b >> 6;
    const int t  = threadIdx.x;
    const int tx = t & 15, ty = t >> 4;
    const int x0 = tx * 4;
    const int wave = t >> 6, lane = t & 63;

    __shared__ float s_d[72];
    __shared__ float s_S;
    __shared__ float s_bias[8], s_mean[8], s_rstd[8];

    if (t < 72) s_d[t] = d_pred[n * 72 + t];
    if (t == 80) s_S = S_in[n];
    if (t >= 88 && t < 96) {
        int o = t - 88;
        s_bias[o] = bias_in[n * 512 + g * 8 + o];
    }

    const float* cbase = content + (size_t)(n * 512 + g * 8) * PLANE;

    // ---- phase 1: stats, one wave per 2 channels (one pass over 8 planes) ----
    #pragma unroll
    for (int jj = 0; jj < 2; ++jj) {
        const int j = wave * 2 + jj;
        const f4* p = (const f4*)(cbase + j * PLANE);
        float s = 0.f, q = 0.f;
        #pragma unroll 4
        for (int k = 0; k < 16; ++k) {
            f4 v = p[lane + 64 * k];
            s += v.x + v.y + v.z + v.w;
            q += v.x * v.x + v.y * v.y + v.z * v.z + v.w * v.w;
        }
        #pragma unroll
        for (int off = 32; off; off >>= 1) {
            s += __shfl_xor(s, off, 64);
            q += __shfl_xor(q, off, 64);
        }
        if (lane == 0) {
            float m = s * (1.f / 4096.f);
            float var = (q - 4096.f * m * m) * (1.f / 4095.f);  // ddof=1
            s_mean[j] = m;
            s_rstd[j] = rsqrtf(var + EPS);
        }
    }
    __syncthreads();

    // ---- phase 2: conv over 4 row-tiles, bounded prefetch window ----
    const float S = s_S;
    #pragma unroll 1
    for (int tile = 0; tile < 4; ++tile) {
        const int h = tile * 16 + ty;
        // row byte-offsets are channel-independent: hoist out of the j-loop
        const int ry0 = (h == 0)  ? 1  : h - 1;   // reflect: -1 -> 1
        const int ry2 = (h == 63) ? 62 : h + 1;   // reflect: 64 -> 62
        const int o0 = ry0 * 64 + x0;
        const int o1 = h   * 64 + x0;
        const int o2 = ry2 * 64 + x0;

        float D0 = 0.f, D1 = 0.f, D2 = 0.f, D3 = 0.f;
        f4 xc[8];

        #pragma unroll 2
        for (int j = 0; j < 8; ++j) {
            const float* cj = cbase + j * PLANE;
            f4 va = *(const f4*)(cj + o0);
            f4 vb = *(const f4*)(cj + o1);
            f4 vc = *(const f4*)(cj + o2);
            xc[j] = vb;
            const float* wj = s_d + j * 9;
            {   // r = 0 (row h-1)
                float lv = __shfl_up(va.w, 1, 64);
                float rv = __shfl_down(va.x, 1, 64);
                float xm = (tx == 0)  ? va.y : lv;
                float xp = (tx == 15) ? va.z : rv;
                D0 += wj[0] * xm   + wj[1] * va.x + wj[2] * va.y;
                D1 += wj[0] * va.x + wj[1] * va.y + wj[2] * va.z;
                D2 += wj[0] * va.y + wj[1] * va.z + wj[2] * va.w;
                D3 += wj[0] * va.z + wj[1] * va.w + wj[2] * xp;
            }
            {   // r = 1 (row h)
                float lv = __shfl_up(vb.w, 1, 64);
                float rv = __shfl_down(vb.x, 1, 64);
                float xm = (tx == 0)  ? vb.y : lv;
                float xp = (tx == 15) ? vb.z : rv;
                D0 += wj[3] * xm   + wj[4] * vb.x + wj[5] * vb.y;
                D1 += wj[3] * vb.x + wj[4] * vb.y + wj[5] * vb.z;
                D2 += wj[3] * vb.y + wj[4] * vb.z + wj[5] * vb.w;
                D3 += wj[3] * vb.z + wj[4] * vb.w + wj[5] * xp;
            }
            {   // r = 2 (row h+1)
                float lv = __shfl_up(vc.w, 1, 64);
                float rv = __shfl_down(vc.x, 1, 64);
                float xm = (tx == 0)  ? vc.y : lv;
                float xp = (tx == 15) ? vc.z : rv;
                D0 += wj[6] * xm   + wj[7] * vc.x + wj[8] * vc.y;
                D1 += wj[6] * vc.x + wj[7] * vc.y + wj[8] * vc.z;
                D2 += wj[6] * vc.y + wj[7] * vc.z + wj[8] * vc.w;
                D3 += wj[6] * vc.z + wj[7] * vc.w + wj[8] * xp;
            }
        }

        const float P0 = D0 * S, P1 = D1 * S, P2 = D2 * S, P3 = D3 * S;
        float* obase = out + (size_t)(n * 512 + g * 8) * PLANE + h * 64 + x0;
        #pragma unroll
        for (int o = 0; o < 8; ++o) {
            float bb = s_bias[o], m = s_mean[o], rs = s_rstd[o];
            f4 res;
            res.x = (xc[o].x - m) * rs * leaky(P0 + bb);
            res.y = (xc[o].y - m) * rs * leaky(P1 + bb);
            res.z = (xc[o].z - m) * rs * leaky(P2 + bb);
            res.w = (xc[o].w - m) * rs * leaky(P3 + bb);
            // NT store: no write-allocate (R6 evidence), keeps content L3-hot
            __builtin_nontemporal_store(res, (f4*)(obase + o * PLANE));
        }
    }
}

extern "C" void kernel_launch(void* const* d_in, const int* in_sizes, int n_in,
                              void* d_out, int out_size, void* d_ws, size_t ws_size,
                              hipStream_t stream) {
    const float* style   = (const float*)d_in[0];
    const float* content = (const float*)d_in[1];
    const float* dw_w    = (const float*)d_in[2];
    const float* dw_b    = (const float*)d_in[3];
    const float* pk_w    = (const float*)d_in[4];
    const float* pk_b    = (const float*)d_in[5];
    const float* pb_w    = (const float*)d_in[6];
    const float* pb_b    = (const float*)d_in[7];
    float* out = (float*)d_out;
    float* ws  = (float*)d_ws;

    const int N = 16;
    float* sd_ws   = ws;                  // N*512
    float* d_pred  = sd_ws + N * 512;     // N*72
    float* S_ws    = d_pred + N * 72;     // N
    float* bias_ws = S_ws + N;            // N*512

    sd_pk_kernel<<<N, 64, 0, stream>>>(style, pk_w, pk_b, sd_ws, S_ws);
    dconv_kernel<<<N * 72 / 4, 256, 0, stream>>>(style, dw_w, dw_b, d_pred);
    bias_kernel<<<512 / 4, 256, 0, stream>>>(sd_ws, pb_w, pb_b, bias_ws);
    main_kernel<<<N * 64, 256, 0, stream>>>(content, d_pred, S_ws, bias_ws, out);
}

// Round 13
// 276.667 us; speedup vs baseline: 1.0822x; 1.0822x over previous
//
#include <hip/hip_runtime.h>
#include <math.h>

#define CH 512
#define P 8
#define PLANE 4096   // 64*64
#define EPS 1e-5f

typedef float f4 __attribute__((ext_vector_type(4)));

__device__ __forceinline__ float leaky(float x) { return x >= 0.f ? x : 0.01f * x; }

__device__ __forceinline__ float wave_sum(float v) {
    #pragma unroll
    for (int off = 32; off; off >>= 1) v += __shfl_xor(v, off, 64);
    return v;
}

// ---------------- Kernel 1a: s_d means + pk dot + S ----------------
// grid = N, block = 64
__global__ __launch_bounds__(64) void sd_pk_kernel(
    const float* __restrict__ style,   // [N,512,4,4]
    const float* __restrict__ pk_w,    // [8,512]
    const float* __restrict__ pk_b,    // [8]
    float* __restrict__ sd_out,        // [N,512]
    float* __restrict__ S_out)         // [N]
{
    const int n = blockIdx.x;
    const int lane = threadIdx.x;
    const float4* sp = (const float4*)(style + (size_t)n * 8192);
    float sd[8];
    #pragma unroll
    for (int i = 0; i < 8; ++i) {
        int c = lane + 64 * i;
        float4 a = sp[c * 4 + 0], b = sp[c * 4 + 1];
        float4 d = sp[c * 4 + 2], e = sp[c * 4 + 3];
        float s = a.x + a.y + a.z + a.w + b.x + b.y + b.z + b.w
                + d.x + d.y + d.z + d.w + e.x + e.y + e.z + e.w;
        sd[i] = s * (1.f / 16.f);
        sd_out[n * 512 + c] = sd[i];
    }
    float Ssum = 0.f;
    #pragma unroll
    for (int o = 0; o < 8; ++o) {
        float acc = 0.f;
        #pragma unroll
        for (int i = 0; i < 8; ++i)
            acc += pk_w[o * 512 + lane + 64 * i] * sd[i];
        Ssum += wave_sum(acc) + pk_b[o];
    }
    if (lane == 0) S_out[n] = Ssum;
}

// ---------------- Kernel 1b: depthwise-kernel predictor conv ----------------
// one wave per (n, j, tap); grid = 16*72/4 = 288, block = 256
__global__ __launch_bounds__(256) void dconv_kernel(
    const float* __restrict__ style,   // [N,512,4,4]
    const float* __restrict__ dw_w,    // [8,512,2,2]
    const float* __restrict__ dw_b,    // [8]
    float* __restrict__ d_pred)        // [N,72]
{
    const int W = blockIdx.x * 4 + (threadIdx.x >> 6);
    const int lane = threadIdx.x & 63;
    const int n = W / 72, r = W % 72;
    const int j = r / 9, pos = r % 9, y = pos / 3, x = pos % 3;
    const float* sb = style + (size_t)n * 8192;
    const float4* wp = (const float4*)dw_w;
    float acc = 0.f;
    #pragma unroll
    for (int i = 0; i < 8; ++i) {
        int c = lane + 64 * i;
        float4 w = wp[j * 512 + c];
        const float* s = sb + c * 16 + y * 4 + x;
        acc += s[0] * w.x + s[1] * w.y + s[4] * w.z + s[5] * w.w;
    }
    acc = wave_sum(acc);
    if (lane == 0) d_pred[n * 72 + r] = leaky(acc + dw_b[j]);
}

// ---------------- Kernel 1c: bias GEMV ----------------
// one wave per output channel c, all 16 n; grid = 512/4 = 128, block = 256
__global__ __launch_bounds__(256) void bias_kernel(
    const float* __restrict__ sd,      // [N,512]
    const float* __restrict__ pb_w,    // [512,512]
    const float* __restrict__ pb_b,    // [512]
    float* __restrict__ bias_out)      // [N,512]
{
    const int c = blockIdx.x * 4 + (threadIdx.x >> 6);
    const int lane = threadIdx.x & 63;
    float w[8];
    #pragma unroll
    for (int i = 0; i < 8; ++i) w[i] = pb_w[(size_t)c * 512 + lane + 64 * i];
    float acc[16];
    #pragma unroll
    for (int nn = 0; nn < 16; ++nn) acc[nn] = 0.f;
    #pragma unroll
    for (int i = 0; i < 8; ++i) {
        #pragma unroll
        for (int nn = 0; nn < 16; ++nn)
            acc[nn] += w[i] * sd[nn * 512 + lane + 64 * i];
    }
    #pragma unroll
    for (int nn = 0; nn < 16; ++nn) acc[nn] = wave_sum(acc[nn]);
    if (lane == 0) {
        float bb = pb_b[c];
        #pragma unroll
        for (int nn = 0; nn < 16; ++nn) bias_out[nn * 512 + c] = acc[nn] + bb;
    }
}

// ---------------- Kernel 2: per-(n,c) instance-norm stats ----------------
// grid = N*512, block = 256
__global__ __launch_bounds__(256) void stats_kernel(
    const float* __restrict__ content,   // [N,512,64,64]
    float* __restrict__ mean_out,        // [N*512]
    float* __restrict__ rstd_out)        // [N*512]
{
    const int nc = blockIdx.x;
    const int t = threadIdx.x;
    const float4* base = (const float4*)(content + (size_t)nc * PLANE);
    float s = 0.f, sq = 0.f;
    #pragma unroll
    for (int k = 0; k < 4; ++k) {
        float4 v = base[k * 256 + t];
        s  += v.x + v.y + v.z + v.w;
        sq += v.x * v.x + v.y * v.y + v.z * v.z + v.w * v.w;
    }
    #pragma unroll
    for (int off = 32; off > 0; off >>= 1) {
        s  += __shfl_down(s, off, 64);
        sq += __shfl_down(sq, off, 64);
    }
    __shared__ float ls[4], lq[4];
    const int wave = t >> 6, lane = t & 63;
    if (lane == 0) { ls[wave] = s; lq[wave] = sq; }
    __syncthreads();
    if (t == 0) {
        float S = ls[0] + ls[1] + ls[2] + ls[3];
        float Q = lq[0] + lq[1] + lq[2] + lq[3];
        float m = S * (1.f / 4096.f);
        float var = (Q - 4096.f * m * m) * (1.f / 4095.f);  // ddof=1
        mean_out[nc] = m;
        rstd_out[nc] = rsqrtf(var + EPS);
    }
}

// ---------------- Kernel 3: fused conv + pointwise-collapse + IN ----------------
// R7 grid (one row-tile per block, 4096 blocks) + R12's 64-VGPR body:
// unroll-2 channel loop (bounded prefetch window), hoisted row offsets.
// 64 VGPR -> 8 waves/SIMD eligible; grid supplies 64 waves/CU of demand.
__global__ __launch_bounds__(256, 4) void main_kernel(
    const float* __restrict__ content,   // [N,512,64,64]
    const float* __restrict__ d_pred,    // [N,72]
    const float* __restrict__ S_in,      // [N]
    const float* __restrict__ bias_in,   // [N,512]
    const float* __restrict__ mean_in,   // [N*512]
    const float* __restrict__ rstd_in,   // [N*512]
    float* __restrict__ out)             // [N,512,64,64]
{
    const int b    = blockIdx.x;
    const int tile = b & 3;
    const int g    = (b >> 2) & 63;
    const int n    = b >> 8;
    const int t  = threadIdx.x;
    const int tx = t & 15, ty = t >> 4;
    const int h  = tile * 16 + ty;
    const int x0 = tx * 4;

    __shared__ float s_d[72];
    __shared__ float s_S;
    __shared__ float s_bias[8], s_mean[8], s_rstd[8];
    if (t < 72) s_d[t] = d_pred[n * 72 + t];
    if (t == 80) s_S = S_in[n];
    if (t >= 88 && t < 96) {
        int o = t - 88;
        int c = n * 512 + g * 8 + o;
        s_bias[o] = bias_in[c];
        s_mean[o] = mean_in[c];
        s_rstd[o] = rstd_in[c];
    }
    __syncthreads();

    const float* cbase = content + (size_t)(n * 512 + g * 8) * PLANE;
    // row offsets are channel-independent: hoist out of the j-loop
    const int ry0 = (h == 0)  ? 1  : h - 1;   // reflect: -1 -> 1
    const int ry2 = (h == 63) ? 62 : h + 1;   // reflect: 64 -> 62
    const int o0 = ry0 * 64 + x0;
    const int o1 = h   * 64 + x0;
    const int o2 = ry2 * 64 + x0;

    float D0 = 0.f, D1 = 0.f, D2 = 0.f, D3 = 0.f;
    f4 xc[8];

    #pragma unroll 2
    for (int j = 0; j < 8; ++j) {
        const float* cj = cbase + j * PLANE;
        f4 va = *(const f4*)(cj + o0);
        f4 vb = *(const f4*)(cj + o1);
        f4 vc = *(const f4*)(cj + o2);
        xc[j] = vb;
        const float* wj = s_d + j * 9;
        {   // r = 0 (row h-1)
            float lv = __shfl_up(va.w, 1, 64);
            float rv = __shfl_down(va.x, 1, 64);
            float xm = (tx == 0)  ? va.y : lv;
            float xp = (tx == 15) ? va.z : rv;
            D0 += wj[0] * xm   + wj[1] * va.x + wj[2] * va.y;
            D1 += wj[0] * va.x + wj[1] * va.y + wj[2] * va.z;
            D2 += wj[0] * va.y + wj[1] * va.z + wj[2] * va.w;
            D3 += wj[0] * va.z + wj[1] * va.w + wj[2] * xp;
        }
        {   // r = 1 (row h)
            float lv = __shfl_up(vb.w, 1, 64);
            float rv = __shfl_down(vb.x, 1, 64);
            float xm = (tx == 0)  ? vb.y : lv;
            float xp = (tx == 15) ? vb.z : rv;
            D0 += wj[3] * xm   + wj[4] * vb.x + wj[5] * vb.y;
            D1 += wj[3] * vb.x + wj[4] * vb.y + wj[5] * vb.z;
            D2 += wj[3] * vb.y + wj[4] * vb.z + wj[5] * vb.w;
            D3 += wj[3] * vb.z + wj[4] * vb.w + wj[5] * xp;
        }
        {   // r = 2 (row h+1)
            float lv = __shfl_up(vc.w, 1, 64);
            float rv = __shfl_down(vc.x, 1, 64);
            float xm = (tx == 0)  ? vc.y : lv;
            float xp = (tx == 15) ? vc.z : rv;
            D0 += wj[6] * xm   + wj[7] * vc.x + wj[8] * vc.y;
            D1 += wj[6] * vc.x + wj[7] * vc.y + wj[8] * vc.z;
            D2 += wj[6] * vc.y + wj[7] * vc.z + wj[8] * vc.w;
            D3 += wj[6] * vc.z + wj[7] * vc.w + wj[8] * xp;
        }
    }

    const float S = s_S;
    const float P0 = D0 * S, P1 = D1 * S, P2 = D2 * S, P3 = D3 * S;
    float* obase = out + (size_t)(n * 512 + g * 8) * PLANE + h * 64 + x0;
    #pragma unroll
    for (int o = 0; o < 8; ++o) {
        float bb = s_bias[o], m = s_mean[o], rs = s_rstd[o];
        f4 res;
        res.x = (xc[o].x - m) * rs * leaky(P0 + bb);
        res.y = (xc[o].y - m) * rs * leaky(P1 + bb);
        res.z = (xc[o].z - m) * rs * leaky(P2 + bb);
        res.w = (xc[o].w - m) * rs * leaky(P3 + bb);
        // NT store: no write-allocate (R6 evidence), keeps content L3-hot
        __builtin_nontemporal_store(res, (f4*)(obase + o * PLANE));
    }
}

extern "C" void kernel_launch(void* const* d_in, const int* in_sizes, int n_in,
                              void* d_out, int out_size, void* d_ws, size_t ws_size,
                              hipStream_t stream) {
    const float* style   = (const float*)d_in[0];
    const float* content = (const float*)d_in[1];
    const float* dw_w    = (const float*)d_in[2];
    const float* dw_b    = (const float*)d_in[3];
    const float* pk_w    = (const float*)d_in[4];
    const float* pk_b    = (const float*)d_in[5];
    const float* pb_w    = (const float*)d_in[6];
    const float* pb_b    = (const float*)d_in[7];
    float* out = (float*)d_out;
    float* ws  = (float*)d_ws;

    const int N = 16;
    float* sd_ws   = ws;                  // N*512
    float* d_pred  = sd_ws + N * 512;     // N*72
    float* S_ws    = d_pred + N * 72;     // N
    float* bias_ws = S_ws + N;            // N*512
    float* mean_ws = bias_ws + N * 512;   // N*512
    float* rstd_ws = mean_ws + N * 512;   // N*512

    sd_pk_kernel<<<N, 64, 0, stream>>>(style, pk_w, pk_b, sd_ws, S_ws);
    dconv_kernel<<<N * 72 / 4, 256, 0, stream>>>(style, dw_w, dw_b, d_pred);
    bias_kernel<<<512 / 4, 256, 0, stream>>>(sd_ws, pb_w, pb_b, bias_ws);
    stats_kernel<<<N * 512, 256, 0, stream>>>(content, mean_ws, rstd_ws);
    main_kernel<<<N * 64 * 4, 256, 0, stream>>>(content, d_pred, S_ws, bias_ws,
                                                mean_ws, rstd_ws, out);
}

// Round 14
// 265.892 us; speedup vs baseline: 1.1260x; 1.0405x over previous
//
#include <hip/hip_runtime.h>
#include <math.h>

#define CH 512
#define P 8
#define PLANE 4096   // 64*64
#define EPS 1e-5f

typedef float f4 __attribute__((ext_vector_type(4)));

__device__ __forceinline__ float leaky(float x) { return x >= 0.f ? x : 0.01f * x; }

__device__ __forceinline__ float wave_sum(float v) {
    #pragma unroll
    for (int off = 32; off; off >>= 1) v += __shfl_xor(v, off, 64);
    return v;
}

// ---------------- Kernel 1: style smalls (sd+S | dconv), co-scheduled ----------
// blocks [0,16):  per-n sd channel-means + S scalar (R2-proven 256-thread body)
// blocks [16,304): dconv, one wave per (n,j,tap) (R7-proven body)
__global__ __launch_bounds__(256) void style_kernel(
    const float* __restrict__ style,   // [N,512,4,4]
    const float* __restrict__ dw_w,    // [8,512,2,2]
    const float* __restrict__ dw_b,    // [8]
    const float* __restrict__ pk_w,    // [8,512]
    const float* __restrict__ pk_b,    // [8]
    float* __restrict__ sd_out,        // [N,512]
    float* __restrict__ S_out,         // [N]
    float* __restrict__ d_pred)        // [N,72]
{
    const int blk = blockIdx.x;
    const int t = threadIdx.x;
    const int wave = t >> 6, lane = t & 63;

    __shared__ float s_sd[512];
    __shared__ float red[4];

    if (blk < 16) {
        const int n = blk;
        const float* sb = style + (size_t)n * 8192;
        #pragma unroll
        for (int qd = 0; qd < 2; ++qd) {
            int c = t + 256 * qd;
            const float4* sp = (const float4*)sb + c * 4;
            float4 a = sp[0], b = sp[1], d = sp[2], e = sp[3];
            float s = a.x + a.y + a.z + a.w + b.x + b.y + b.z + b.w
                    + d.x + d.y + d.z + d.w + e.x + e.y + e.z + e.w;
            s *= (1.f / 16.f);
            s_sd[c] = s;
            sd_out[n * 512 + c] = s;
        }
        __syncthreads();
        float part = 0.f;
        #pragma unroll
        for (int o = 0; o < 8; ++o)
            part += pk_w[o * 512 + t] * s_sd[t]
                  + pk_w[o * 512 + t + 256] * s_sd[t + 256];
        part = wave_sum(part);
        if (lane == 0) red[wave] = part;
        __syncthreads();
        if (t == 0) {
            float S = red[0] + red[1] + red[2] + red[3];
            #pragma unroll
            for (int o = 0; o < 8; ++o) S += pk_b[o];
            S_out[n] = S;
        }
    } else {
        const int W = (blk - 16) * 4 + wave;   // 288 blocks x 4 waves = 1152
        const int n = W / 72, r = W % 72;
        const int j = r / 9, pos = r % 9, y = pos / 3, x = pos % 3;
        const float* sb = style + (size_t)n * 8192;
        const float4* wp = (const float4*)dw_w;
        float acc = 0.f;
        #pragma unroll
        for (int i = 0; i < 8; ++i) {
            int c = lane + 64 * i;
            float4 w = wp[j * 512 + c];
            const float* s = sb + c * 16 + y * 4 + x;
            acc += s[0] * w.x + s[1] * w.y + s[4] * w.z + s[5] * w.w;
        }
        acc = wave_sum(acc);
        if (lane == 0) d_pred[n * 72 + r] = leaky(acc + dw_b[j]);
    }
}

// ---------------- Kernel 2: bias GEMV (first 128 blocks) | IN stats ------------
// blocks [0,128): bias, one wave per output channel c, all 16 n (R7 body)
// blocks [128, 128+8192): per-(n,c) stats, nc = blk-128 (R7 body)
// bias blocks lead the grid so they dispatch first and hide under stats.
__global__ __launch_bounds__(256) void bias_stats_kernel(
    const float* __restrict__ content,   // [N,512,64,64]
    const float* __restrict__ sd,        // [N,512]
    const float* __restrict__ pb_w,      // [512,512]
    const float* __restrict__ pb_b,      // [512]
    float* __restrict__ bias_out,        // [N,512]
    float* __restrict__ mean_out,        // [N*512]
    float* __restrict__ rstd_out)        // [N*512]
{
    const int blk = blockIdx.x;
    const int t = threadIdx.x;
    const int wave = t >> 6, lane = t & 63;

    __shared__ float ls[4], lq[4];

    if (blk < 128) {
        const int c = blk * 4 + wave;
        float w[8];
        #pragma unroll
        for (int i = 0; i < 8; ++i) w[i] = pb_w[(size_t)c * 512 + lane + 64 * i];
        float acc[16];
        #pragma unroll
        for (int nn = 0; nn < 16; ++nn) acc[nn] = 0.f;
        #pragma unroll
        for (int i = 0; i < 8; ++i) {
            #pragma unroll
            for (int nn = 0; nn < 16; ++nn)
                acc[nn] += w[i] * sd[nn * 512 + lane + 64 * i];
        }
        #pragma unroll
        for (int nn = 0; nn < 16; ++nn) acc[nn] = wave_sum(acc[nn]);
        if (lane == 0) {
            float bb = pb_b[c];
            #pragma unroll
            for (int nn = 0; nn < 16; ++nn) bias_out[nn * 512 + c] = acc[nn] + bb;
        }
    } else {
        const int nc = blk - 128;
        const float4* base = (const float4*)(content + (size_t)nc * PLANE);
        float s = 0.f, sq = 0.f;
        #pragma unroll
        for (int k = 0; k < 4; ++k) {
            float4 v = base[k * 256 + t];
            s  += v.x + v.y + v.z + v.w;
            sq += v.x * v.x + v.y * v.y + v.z * v.z + v.w * v.w;
        }
        #pragma unroll
        for (int off = 32; off > 0; off >>= 1) {
            s  += __shfl_down(s, off, 64);
            sq += __shfl_down(sq, off, 64);
        }
        if (lane == 0) { ls[wave] = s; lq[wave] = sq; }
        __syncthreads();
        if (t == 0) {
            float S = ls[0] + ls[1] + ls[2] + ls[3];
            float Q = lq[0] + lq[1] + lq[2] + lq[3];
            float m = S * (1.f / 4096.f);
            float var = (Q - 4096.f * m * m) * (1.f / 4095.f);  // ddof=1
            mean_out[nc] = m;
            rstd_out[nc] = rsqrtf(var + EPS);
        }
    }
}

// ---------------- Kernel 3: fused conv + pointwise-collapse + IN ---------------
// R13's best-measured body, byte-identical: 64-VGPR unroll-2 channel loop,
// hoisted row offsets, shfl x-halo, NT stores. grid = N*64*4 = 4096.
__global__ __launch_bounds__(256, 4) void main_kernel(
    const float* __restrict__ content,   // [N,512,64,64]
    const float* __restrict__ d_pred,    // [N,72]
    const float* __restrict__ S_in,      // [N]
    const float* __restrict__ bias_in,   // [N,512]
    const float* __restrict__ mean_in,   // [N*512]
    const float* __restrict__ rstd_in,   // [N*512]
    float* __restrict__ out)             // [N,512,64,64]
{
    const int b    = blockIdx.x;
    const int tile = b & 3;
    const int g    = (b >> 2) & 63;
    const int n    = b >> 8;
    const int t  = threadIdx.x;
    const int tx = t & 15, ty = t >> 4;
    const int h  = tile * 16 + ty;
    const int x0 = tx * 4;

    __shared__ float s_d[72];
    __shared__ float s_S;
    __shared__ float s_bias[8], s_mean[8], s_rstd[8];
    if (t < 72) s_d[t] = d_pred[n * 72 + t];
    if (t == 80) s_S = S_in[n];
    if (t >= 88 && t < 96) {
        int o = t - 88;
        int c = n * 512 + g * 8 + o;
        s_bias[o] = bias_in[c];
        s_mean[o] = mean_in[c];
        s_rstd[o] = rstd_in[c];
    }
    __syncthreads();

    const float* cbase = content + (size_t)(n * 512 + g * 8) * PLANE;
    const int ry0 = (h == 0)  ? 1  : h - 1;   // reflect: -1 -> 1
    const int ry2 = (h == 63) ? 62 : h + 1;   // reflect: 64 -> 62
    const int o0 = ry0 * 64 + x0;
    const int o1 = h   * 64 + x0;
    const int o2 = ry2 * 64 + x0;

    float D0 = 0.f, D1 = 0.f, D2 = 0.f, D3 = 0.f;
    f4 xc[8];

    #pragma unroll 2
    for (int j = 0; j < 8; ++j) {
        const float* cj = cbase + j * PLANE;
        f4 va = *(const f4*)(cj + o0);
        f4 vb = *(const f4*)(cj + o1);
        f4 vc = *(const f4*)(cj + o2);
        xc[j] = vb;
        const float* wj = s_d + j * 9;
        {   // r = 0 (row h-1)
            float lv = __shfl_up(va.w, 1, 64);
            float rv = __shfl_down(va.x, 1, 64);
            float xm = (tx == 0)  ? va.y : lv;
            float xp = (tx == 15) ? va.z : rv;
            D0 += wj[0] * xm   + wj[1] * va.x + wj[2] * va.y;
            D1 += wj[0] * va.x + wj[1] * va.y + wj[2] * va.z;
            D2 += wj[0] * va.y + wj[1] * va.z + wj[2] * va.w;
            D3 += wj[0] * va.z + wj[1] * va.w + wj[2] * xp;
        }
        {   // r = 1 (row h)
            float lv = __shfl_up(vb.w, 1, 64);
            float rv = __shfl_down(vb.x, 1, 64);
            float xm = (tx == 0)  ? vb.y : lv;
            float xp = (tx == 15) ? vb.z : rv;
            D0 += wj[3] * xm   + wj[4] * vb.x + wj[5] * vb.y;
            D1 += wj[3] * vb.x + wj[4] * vb.y + wj[5] * vb.z;
            D2 += wj[3] * vb.y + wj[4] * vb.z + wj[5] * vb.w;
            D3 += wj[3] * vb.z + wj[4] * vb.w + wj[5] * xp;
        }
        {   // r = 2 (row h+1)
            float lv = __shfl_up(vc.w, 1, 64);
            float rv = __shfl_down(vc.x, 1, 64);
            float xm = (tx == 0)  ? vc.y : lv;
            float xp = (tx == 15) ? vc.z : rv;
            D0 += wj[6] * xm   + wj[7] * vc.x + wj[8] * vc.y;
            D1 += wj[6] * vc.x + wj[7] * vc.y + wj[8] * vc.z;
            D2 += wj[6] * vc.y + wj[7] * vc.z + wj[8] * vc.w;
            D3 += wj[6] * vc.z + wj[7] * vc.w + wj[8] * xp;
        }
    }

    const float S = s_S;
    const float P0 = D0 * S, P1 = D1 * S, P2 = D2 * S, P3 = D3 * S;
    float* obase = out + (size_t)(n * 512 + g * 8) * PLANE + h * 64 + x0;
    #pragma unroll
    for (int o = 0; o < 8; ++o) {
        float bb = s_bias[o], m = s_mean[o], rs = s_rstd[o];
        f4 res;
        res.x = (xc[o].x - m) * rs * leaky(P0 + bb);
        res.y = (xc[o].y - m) * rs * leaky(P1 + bb);
        res.z = (xc[o].z - m) * rs * leaky(P2 + bb);
        res.w = (xc[o].w - m) * rs * leaky(P3 + bb);
        // NT store: no write-allocate amplification (R6 evidence: 2.6x)
        __builtin_nontemporal_store(res, (f4*)(obase + o * PLANE));
    }
}

extern "C" void kernel_launch(void* const* d_in, const int* in_sizes, int n_in,
                              void* d_out, int out_size, void* d_ws, size_t ws_size,
                              hipStream_t stream) {
    const float* style   = (const float*)d_in[0];
    const float* content = (const float*)d_in[1];
    const float* dw_w    = (const float*)d_in[2];
    const float* dw_b    = (const float*)d_in[3];
    const float* pk_w    = (const float*)d_in[4];
    const float* pk_b    = (const float*)d_in[5];
    const float* pb_w    = (const float*)d_in[6];
    const float* pb_b    = (const float*)d_in[7];
    float* out = (float*)d_out;
    float* ws  = (float*)d_ws;

    const int N = 16;
    float* sd_ws   = ws;                  // N*512
    float* d_pred  = sd_ws + N * 512;     // N*72
    float* S_ws    = d_pred + N * 72;     // N
    float* bias_ws = S_ws + N;            // N*512
    float* mean_ws = bias_ws + N * 512;   // N*512
    float* rstd_ws = mean_ws + N * 512;   // N*512

    style_kernel<<<16 + 288, 256, 0, stream>>>(style, dw_w, dw_b, pk_w, pk_b,
                                               sd_ws, S_ws, d_pred);
    bias_stats_kernel<<<128 + N * 512, 256, 0, stream>>>(
        content, sd_ws, pb_w, pb_b, bias_ws, mean_ws, rstd_ws);
    main_kernel<<<N * 64 * 4, 256, 0, stream>>>(content, d_pred, S_ws, bias_ws,
                                                mean_ws, rstd_ws, out);
}